// Round 5
// baseline (743.281 us; speedup 1.0000x reference)
//
#include <hip/hip_runtime.h>
#include <hip/hip_fp16.h>
#include <math.h>

// ---------------------------------------------------------------------------
// SovereignLeviathanV2  round 5 = round 4 + occupancy/ILP restructure:
//  - k_phi: 64x128 tiles, grid 1024 (4 blocks/CU, 16 waves/CU),
//    conflict-free *4-stride micro reads, launch_bounds(256,4).
//  - k_ffn: 1024 thr / 16 waves (4/SIMD), F-strip 512 (4 iters, 8 barriers),
//    per-wave c-block 32 (acc 32 VGPR), launch_bounds(1024,4).
// Everything else unchanged from the passing round-4 kernel.
// ---------------------------------------------------------------------------

#define PI_F 3.14159265358979323846f
#define HARM_F 1.04719755119659774615f
#define INV_HARM_F 0.95492965855137201461f
#define TOL_F 0.15f

typedef float f32x16 __attribute__((ext_vector_type(16)));
typedef __bf16 bf16x8 __attribute__((ext_vector_type(8)));
typedef unsigned int u32x4 __attribute__((ext_vector_type(4)));
typedef unsigned int u32x2 __attribute__((ext_vector_type(2)));

__device__ __forceinline__ float gelu_tanh(float x) {
  float x3 = x * x * x;
  return 0.5f * x * (1.f + tanhf(0.79788456080286535588f * (x + 0.044715f * x3)));
}
__device__ __forceinline__ unsigned short f2bf(float x) {
  unsigned u = __float_as_uint(x);
  unsigned r = (u + 0x7FFFu + ((u >> 16) & 1u)) >> 16;
  return (unsigned short)r;
}
__device__ __forceinline__ float bflo(unsigned u) { return __uint_as_float(u << 16); }
__device__ __forceinline__ float bfhi(unsigned u) { return __uint_as_float(u & 0xFFFF0000u); }
__device__ __forceinline__ bf16x8 ld_frag(const void* p) {
  u32x4 v = *(const u32x4*)p;
  return __builtin_bit_cast(bf16x8, v);
}

// K1: X[n][c] = emb[seq[n]][c]
__global__ void k_embed(const int* __restrict__ seq, const float* __restrict__ emb,
                        float* __restrict__ X) {
  int i = blockIdx.x * 256 + threadIdx.x;
  int n = i >> 7, c4 = i & 127;
  int tok = seq[n];
  ((float4*)X)[(size_t)n * 128 + c4] = ((const float4*)emb)[(size_t)tok * 128 + c4];
}

// ---------------------------------------------------------------------------
// Generic B-operand frag pack: src fp32 [K][N] (row-major, leading dim ld)
// -> bf16 frag entries. Entry (nb, ksGlobal): 64 lanes x 16B, lane l holds
// src[ksGlobal*16 + (l>>5)*8 + j][nb*32 + (l&31)], j=0..7.
// grid: (nb, kseg(512-row slabs), e)
// ---------------------------------------------------------------------------
__global__ __launch_bounds__(256) void k_pack_b(const float* __restrict__ src, int ld,
                                                size_t srcE, unsigned short* __restrict__ dst,
                                                size_t dstE, int fragKtot) {
  __shared__ float Ls[512 * 33];
  int nb = blockIdx.x, kseg = blockIdx.y, e = blockIdx.z;
  const float* s = src + (size_t)e * srcE + (size_t)kseg * 512 * ld + nb * 32;
  unsigned short* d = dst + (size_t)e * dstE + ((size_t)(nb * fragKtot + kseg * 32)) * 512;
  int tid = threadIdx.x;
#pragma unroll
  for (int q = 0; q < 16; ++q) {
    int i = tid + q * 256;
    int row = i >> 3, c4 = i & 7;
    float4 v = *(const float4*)(s + (size_t)row * ld + c4 * 4);
    Ls[row * 33 + c4 * 4 + 0] = v.x;
    Ls[row * 33 + c4 * 4 + 1] = v.y;
    Ls[row * 33 + c4 * 4 + 2] = v.z;
    Ls[row * 33 + c4 * 4 + 3] = v.w;
  }
  __syncthreads();
#pragma unroll
  for (int q = 0; q < 8; ++q) {
    int i = tid + q * 256;
    int ks = i >> 6, l = i & 63;
    int col = l & 31, kb = (l >> 5) * 8 + ks * 16;
    u32x4 o;
    o.x = (unsigned)f2bf(Ls[(kb + 0) * 33 + col]) | ((unsigned)f2bf(Ls[(kb + 1) * 33 + col]) << 16);
    o.y = (unsigned)f2bf(Ls[(kb + 2) * 33 + col]) | ((unsigned)f2bf(Ls[(kb + 3) * 33 + col]) << 16);
    o.z = (unsigned)f2bf(Ls[(kb + 4) * 33 + col]) | ((unsigned)f2bf(Ls[(kb + 5) * 33 + col]) << 16);
    o.w = (unsigned)f2bf(Ls[(kb + 6) * 33 + col]) | ((unsigned)f2bf(Ls[(kb + 7) * 33 + col]) << 16);
    *(u32x4*)(d + (size_t)ks * 512 + l * 8) = o;
  }
}

// ---------------------------------------------------------------------------
// K2: fused phi+amp fp32 GEMM. M=8192, K=512, N=1024 (by<4: phi, else amp).
// 64x128 tile, BK=16, 4x8 microtile (cols split tx*4 / 64+tx*4), dbuf LDS.
// ---------------------------------------------------------------------------
__global__ __launch_bounds__(256, 4) void k_phi(const float* __restrict__ A,
                                                const float* __restrict__ phiW,
                                                const float* __restrict__ phiB,
                                                const float* __restrict__ ampW,
                                                const float* __restrict__ ampB,
                                                float* __restrict__ cosO,
                                                float* __restrict__ sinO,
                                                float* __restrict__ sigO) {
  __shared__ float As[2][16 * 68];
  __shared__ float Bs[2][16 * 132];
  int tid = threadIdx.x;
  int tx = tid & 15, ty = tid >> 4;
  int bm = blockIdx.x * 64;
  int by = blockIdx.y;
  const float* Bsrc = (by < 4) ? phiW : ampW;
  const float* bias = (by < 4) ? phiB : ampB;
  int cb = (by & 3) * 128;
  float acc[4][8];
#pragma unroll
  for (int r = 0; r < 4; ++r)
#pragma unroll
    for (int c = 0; c < 8; ++c) acc[r][c] = 0.f;

#define STAGE_PHI(BUF, KT)                                                     \
  {                                                                            \
    {                                                                          \
      int row = tid >> 2, kq = tid & 3;                                        \
      float4 v = *(const float4*)(A + (size_t)(bm + row) * 512 + (KT)*16 + kq * 4); \
      As[BUF][(kq * 4 + 0) * 68 + row] = v.x;                                  \
      As[BUF][(kq * 4 + 1) * 68 + row] = v.y;                                  \
      As[BUF][(kq * 4 + 2) * 68 + row] = v.z;                                  \
      As[BUF][(kq * 4 + 3) * 68 + row] = v.w;                                  \
    }                                                                          \
    _Pragma("unroll") for (int s = 0; s < 2; ++s) {                            \
      int i = tid + s * 256;                                                   \
      int kk = i >> 5, g = i & 31;                                             \
      float4 v = *(const float4*)(Bsrc + (size_t)((KT)*16 + kk) * 512 + cb + g * 4); \
      *(float4*)(&Bs[BUF][kk * 132 + g * 4]) = v;                              \
    }                                                                          \
  }

  STAGE_PHI(0, 0);
  for (int kt = 0; kt < 32; ++kt) {
    __syncthreads();
    if (kt + 1 < 32) {
      if ((kt & 1) == 0) STAGE_PHI(1, kt + 1) else STAGE_PHI(0, kt + 1)
    }
    const float* Ab = As[kt & 1];
    const float* Bb = Bs[kt & 1];
#pragma unroll
    for (int kk = 0; kk < 16; ++kk) {
      float4 a = *(const float4*)(&Ab[kk * 68 + ty * 4]);
      float4 b0 = *(const float4*)(&Bb[kk * 132 + tx * 4]);
      float4 b1 = *(const float4*)(&Bb[kk * 132 + 64 + tx * 4]);
      float ar[4] = {a.x, a.y, a.z, a.w};
      float br[8] = {b0.x, b0.y, b0.z, b0.w, b1.x, b1.y, b1.z, b1.w};
#pragma unroll
      for (int r = 0; r < 4; ++r)
#pragma unroll
        for (int c = 0; c < 8; ++c) acc[r][c] = fmaf(ar[r], br[c], acc[r][c]);
    }
  }
  // epilogue: rows bm+ty*4+r; cols cb+tx*4+{0..3} and cb+64+tx*4+{0..3}
#pragma unroll
  for (int r = 0; r < 4; ++r) {
    int m = bm + ty * 4 + r;
    float o0[8];
    if (by < 4) {
      float o1[8];
#pragma unroll
      for (int c = 0; c < 8; ++c) {
        int col = cb + ((c < 4) ? 0 : 64) + tx * 4 + (c & 3);
        float z = acc[r][c] + bias[col];
        float a = tanhf(z) * PI_F;
        float nr = rintf(a * INV_HARM_F) * HARM_F;
        if (fabsf(a - nr) < TOL_F) a = nr;
        float sn, cs;
        sincosf(a, &sn, &cs);
        o0[c] = cs;
        o1[c] = sn;
      }
      float* cp = cosO + (size_t)m * 512 + cb + tx * 4;
      float* sp = sinO + (size_t)m * 512 + cb + tx * 4;
      *(float4*)cp = make_float4(o0[0], o0[1], o0[2], o0[3]);
      *(float4*)(cp + 64) = make_float4(o0[4], o0[5], o0[6], o0[7]);
      *(float4*)sp = make_float4(o1[0], o1[1], o1[2], o1[3]);
      *(float4*)(sp + 64) = make_float4(o1[4], o1[5], o1[6], o1[7]);
    } else {
#pragma unroll
      for (int c = 0; c < 8; ++c) {
        int col = cb + ((c < 4) ? 0 : 64) + tx * 4 + (c & 3);
        float z = acc[r][c] + bias[col];
        o0[c] = 1.f / (1.f + expf(-z));
      }
      float* gp = sigO + (size_t)m * 512 + cb + tx * 4;
      *(float4*)gp = make_float4(o0[0], o0[1], o0[2], o0[3]);
      *(float4*)(gp + 64) = make_float4(o0[4], o0[5], o0[6], o0[7]);
    }
  }
}

// K3: toroidal scan, 4-buffer rotating prefetch. 32 blocks x 64 threads.
__global__ void k_scan(const float* __restrict__ cosb, const float* __restrict__ sinb,
                       const float* __restrict__ sigb, float* __restrict__ xmoe,
                       float* __restrict__ nstate) {
  int gid = blockIdx.x * 64 + threadIdx.x;  // 0..2047
  size_t b = gid >> 9, c = gid & 511;
  size_t base = (b * 2048) * 512 + c;
  float state = 0.f;
  float C0[8], S0[8], G0[8], C1[8], S1[8], G1[8];
  float C2[8], S2[8], G2[8], C3[8], S3[8], G3[8];
#define LOADB(CB, SB, GB, blk)                                                  \
  {                                                                             \
    int bb = (blk) < 255 ? (blk) : 255;                                         \
    size_t o = base + (size_t)bb * 8 * 512;                                     \
    _Pragma("unroll") for (int j = 0; j < 8; ++j) {                             \
      size_t oo = o + (size_t)j * 512;                                          \
      CB[j] = cosb[oo]; SB[j] = sinb[oo]; GB[j] = sigb[oo];                     \
    }                                                                           \
  }
#define COMPB(CB, SB, GB, blk)                                                  \
  {                                                                             \
    size_t o = base + (size_t)(blk)*8 * 512;                                    \
    _Pragma("unroll") for (int j = 0; j < 8; ++j) {                             \
      float st = fmaf(SB[j], state, -SB[j]);                                    \
      st = fmaf(CB[j], state, st);                                              \
      st = fminf(1.f, fmaxf(-1.f, st));                                         \
      state = st;                                                               \
      xmoe[o + (size_t)j * 512] = GB[j] * st;                                   \
    }                                                                           \
  }
  LOADB(C0, S0, G0, 0);
  LOADB(C1, S1, G1, 1);
  LOADB(C2, S2, G2, 2);
  for (int i = 0; i < 64; ++i) {
    LOADB(C3, S3, G3, 4 * i + 3);
    COMPB(C0, S0, G0, 4 * i);
    LOADB(C0, S0, G0, 4 * i + 4);
    COMPB(C1, S1, G1, 4 * i + 1);
    LOADB(C1, S1, G1, 4 * i + 5);
    COMPB(C2, S2, G2, 4 * i + 2);
    LOADB(C2, S2, G2, 4 * i + 6);
    COMPB(C3, S3, G3, 4 * i + 3);
  }
  nstate[gid] = state;
}

// K4: gate logits + softmax + top2 -> packed e01p/w01p
__global__ __launch_bounds__(256) void k_gate(const float* __restrict__ xmoe,
                                              const float* __restrict__ gw_g,
                                              const float* __restrict__ gb,
                                              int* __restrict__ e01p,
                                              unsigned* __restrict__ w01p) {
  __shared__ float gw[4096];
  int tid = threadIdx.x;
  for (int i = tid; i < 4096; i += 256) gw[i] = gw_g[i];
  __syncthreads();
  int tok = blockIdx.x * 32 + (tid >> 3);
  int e = tid & 7;
  float acc = gb[e];
  const float4* xr = (const float4*)(xmoe + (size_t)tok * 512);
  for (int k4 = 0; k4 < 128; ++k4) {
    float4 x = xr[k4];
    acc += x.x * gw[(k4 * 4 + 0) * 8 + e];
    acc += x.y * gw[(k4 * 4 + 1) * 8 + e];
    acc += x.z * gw[(k4 * 4 + 2) * 8 + e];
    acc += x.w * gw[(k4 * 4 + 3) * 8 + e];
  }
  float m = acc;
  m = fmaxf(m, __shfl_xor(m, 1));
  m = fmaxf(m, __shfl_xor(m, 2));
  m = fmaxf(m, __shfl_xor(m, 4));
  float p = expf(acc - m);
  float ss = p;
  ss += __shfl_xor(ss, 1); ss += __shfl_xor(ss, 2); ss += __shfl_xor(ss, 4);
  p /= ss;
  float v1 = p; int i1 = e;
  {
    float ov; int oi;
    ov = __shfl_xor(v1, 1); oi = __shfl_xor(i1, 1);
    if (ov > v1 || (ov == v1 && oi < i1)) { v1 = ov; i1 = oi; }
    ov = __shfl_xor(v1, 2); oi = __shfl_xor(i1, 2);
    if (ov > v1 || (ov == v1 && oi < i1)) { v1 = ov; i1 = oi; }
    ov = __shfl_xor(v1, 4); oi = __shfl_xor(i1, 4);
    if (ov > v1 || (ov == v1 && oi < i1)) { v1 = ov; i1 = oi; }
  }
  float v2 = (e == i1) ? -1.f : p; int i2 = e;
  {
    float ov; int oi;
    ov = __shfl_xor(v2, 1); oi = __shfl_xor(i2, 1);
    if (ov > v2 || (ov == v2 && oi < i2)) { v2 = ov; i2 = oi; }
    ov = __shfl_xor(v2, 2); oi = __shfl_xor(i2, 2);
    if (ov > v2 || (ov == v2 && oi < i2)) { v2 = ov; i2 = oi; }
    ov = __shfl_xor(v2, 4); oi = __shfl_xor(i2, 4);
    if (ov > v2 || (ov == v2 && oi < i2)) { v2 = ov; i2 = oi; }
  }
  if (e == 0) {
    float s2 = v1 + v2;
    __half h1 = __float2half(v1 / s2), h2 = __float2half(v2 / s2);
    e01p[tok] = i1 | (i2 << 8);
    w01p[tok] = (unsigned)__half_as_ushort(h1) | ((unsigned)__half_as_ushort(h2) << 16);
  }
}

// K6: counts -> eoff prefix -> scatter (list/wlist/tokpos), 1 block
__global__ void k_build(const int* __restrict__ e01p, const unsigned* __restrict__ w01p,
                        int* __restrict__ list, float* __restrict__ wlist,
                        int* __restrict__ counts, int* __restrict__ eoff,
                        int* __restrict__ tokpos) {
  __shared__ int cnt[8], cur[8];
  int tid = threadIdx.x, lane = tid & 63;
  if (tid < 8) cnt[tid] = 0;
  __syncthreads();
  for (int i = tid; i < 16384; i += 256) {
    int tok = i >> 1, j = i & 1;
    int ee = (e01p[tok] >> (8 * j)) & 255;
#pragma unroll
    for (int x = 0; x < 8; ++x) {
      unsigned long long m = __ballot(ee == x);
      if (m != 0ull && lane == (__ffsll((long long)m) - 1)) atomicAdd(&cnt[x], __popcll(m));
    }
  }
  __syncthreads();
  if (tid == 0) {
    int s = 0;
#pragma unroll
    for (int x = 0; x < 8; ++x) {
      cur[x] = s; eoff[x] = s; counts[x] = cnt[x]; s += cnt[x];
    }
  }
  __syncthreads();
  for (int i = tid; i < 16384; i += 256) {
    int tok = i >> 1, j = i & 1;
    int ee = (e01p[tok] >> (8 * j)) & 255;
    unsigned wp = w01p[tok];
    unsigned short us = (unsigned short)(j ? (wp >> 16) : (wp & 0xFFFFu));
    float w = __half2float(__ushort_as_half(us));
    int pos = 0;
#pragma unroll
    for (int x = 0; x < 8; ++x) {
      unsigned long long m = __ballot(ee == x);
      if (m == 0ull) continue;
      int leader = __ffsll((long long)m) - 1;
      int bb = 0;
      if (lane == leader) bb = atomicAdd(&cur[x], __popcll(m));
      bb = __shfl(bb, leader);
      if (ee == x) pos = bb + __popcll(m & ((1ull << lane) - 1ull));
    }
    list[pos] = tok;
    wlist[pos] = w;
    tokpos[i] = pos;
  }
}

// ---------------------------------------------------------------------------
// K7: fused MoE FFN. Block = (expert, 64-token tile), 1024 thr / 16 waves
// (4 waves/SIMD). F-loop: 4 strips of 512. GEMM1: wave w = f-block (32 f);
// gelu -> Hs (64 tok x 512 f). GEMM2: wave w = c-block (32 c), K = 512 strip.
// W1/W2 streamed frag-packed global->reg. Epilogue: (+b2)*wt -> bf16 ->
// LDS bounce -> Yb rows. LDS 128.5KB, 1 block/CU.
// ---------------------------------------------------------------------------
#define HS_OFF 65536

__global__ __launch_bounds__(1024, 4) void k_ffn(
    const float* __restrict__ xmoe, const int* __restrict__ list,
    const float* __restrict__ wlist, const int* __restrict__ counts,
    const int* __restrict__ eoff,
    const unsigned short* __restrict__ W1Pk, const float* __restrict__ b1g,
    const unsigned short* __restrict__ W2Pk, const float* __restrict__ b2g,
    unsigned short* __restrict__ Yb) {
  int e = blockIdx.y, tile = blockIdx.x;
  int cnt = counts[e];
  if (tile * 64 >= cnt) return;
  int base = eoff[e] + tile * 64;
  int valid = cnt - tile * 64;
  if (valid > 64) valid = 64;
  __shared__ __align__(16) char smem[131072];
  __shared__ int toks[64];
  __shared__ float wts[64];
  int tid = threadIdx.x;
  int w = tid >> 6, l = tid & 63;
  int l31 = l & 31, hi = l >> 5;
  int sw = (l31 & 7) << 4;
  if (tid < 64) {
    int idx = tile * 64 + tid;
    bool v = idx < cnt;
    toks[tid] = list[eoff[e] + (v ? idx : 0)];
    wts[tid] = v ? wlist[eoff[e] + idx] : 0.f;
  }
  __syncthreads();
  // stage Xs: 64 rows x 512 bf16, XOR-swizzled 16B units
#pragma unroll
  for (int s = 0; s < 4; ++s) {
    int i = tid + s * 1024;
    int row = i >> 6, g = i & 63;
    const float* src = xmoe + (size_t)toks[row] * 512 + g * 8;
    float4 v0 = *(const float4*)src;
    float4 v1 = *(const float4*)(src + 4);
    u32x4 u;
    u.x = (unsigned)f2bf(v0.x) | ((unsigned)f2bf(v0.y) << 16);
    u.y = (unsigned)f2bf(v0.z) | ((unsigned)f2bf(v0.w) << 16);
    u.z = (unsigned)f2bf(v1.x) | ((unsigned)f2bf(v1.y) << 16);
    u.w = (unsigned)f2bf(v1.z) | ((unsigned)f2bf(v1.w) << 16);
    *(u32x4*)(smem + row * 1024 + ((g * 16) ^ ((row & 7) << 4))) = u;
  }
  f32x16 acc0, acc1;
#pragma unroll
  for (int i = 0; i < 16; ++i) { acc0[i] = 0.f; acc1[i] = 0.f; }
  __syncthreads();

  for (int it = 0; it < 4; ++it) {
    // ---- GEMM1: wave w = f-block (32 f of strip 512) ----
    f32x16 z0, z1;
#pragma unroll
    for (int i = 0; i < 16; ++i) { z0[i] = 0.f; z1[i] = 0.f; }
    const unsigned short* w1p =
        W1Pk + (((size_t)e * 64 + it * 16 + w) * 32) * 512 + l * 8;
#pragma unroll 8
    for (int ks = 0; ks < 32; ++ks) {
      bf16x8 a = *(const bf16x8*)(w1p + (size_t)ks * 512);
      int kb = ks * 32 + hi * 16;
      bf16x8 b0 = ld_frag(smem + l31 * 1024 + (kb ^ sw));
      bf16x8 b1 = ld_frag(smem + (l31 + 32) * 1024 + (kb ^ sw));
      z0 = __builtin_amdgcn_mfma_f32_32x32x16_bf16(a, b0, z0, 0, 0, 0);
      z1 = __builtin_amdgcn_mfma_f32_32x32x16_bf16(a, b1, z1, 0, 0, 0);
    }
    // bias + gelu -> Hs (row = tok, col = strip-local f, row stride 1KB)
#pragma unroll
    for (int rq = 0; rq < 4; ++rq) {
      int f0 = 8 * rq + 4 * hi;
      float4 bv = *(const float4*)(b1g + e * 2048 + it * 512 + w * 32 + f0);
      float g0 = gelu_tanh(z0[4 * rq + 0] + bv.x);
      float g1 = gelu_tanh(z0[4 * rq + 1] + bv.y);
      float g2 = gelu_tanh(z0[4 * rq + 2] + bv.z);
      float g3 = gelu_tanh(z0[4 * rq + 3] + bv.w);
      u32x2 p;
      p.x = (unsigned)f2bf(g0) | ((unsigned)f2bf(g1) << 16);
      p.y = (unsigned)f2bf(g2) | ((unsigned)f2bf(g3) << 16);
      *(u32x2*)(smem + HS_OFF + l31 * 1024 + (((w * 32 + f0) * 2) ^ sw)) = p;
      g0 = gelu_tanh(z1[4 * rq + 0] + bv.x);
      g1 = gelu_tanh(z1[4 * rq + 1] + bv.y);
      g2 = gelu_tanh(z1[4 * rq + 2] + bv.z);
      g3 = gelu_tanh(z1[4 * rq + 3] + bv.w);
      p.x = (unsigned)f2bf(g0) | ((unsigned)f2bf(g1) << 16);
      p.y = (unsigned)f2bf(g2) | ((unsigned)f2bf(g3) << 16);
      *(u32x2*)(smem + HS_OFF + (l31 + 32) * 1024 + (((w * 32 + f0) * 2) ^ sw)) = p;
    }
    __syncthreads();
    // ---- GEMM2: wave w = c-block (32 c), K = strip 512 ----
    const unsigned short* w2p =
        W2Pk + (((size_t)e * 16 + w) * 128 + it * 32) * 512 + l * 8;
#pragma unroll 8
    for (int fs = 0; fs < 32; ++fs) {
      bf16x8 a = *(const bf16x8*)(w2p + (size_t)fs * 512);
      int fb = fs * 32 + hi * 16;
      bf16x8 h0 = ld_frag(smem + HS_OFF + l31 * 1024 + (fb ^ sw));
      bf16x8 h1 = ld_frag(smem + HS_OFF + (l31 + 32) * 1024 + (fb ^ sw));
      acc0 = __builtin_amdgcn_mfma_f32_32x32x16_bf16(a, h0, acc0, 0, 0, 0);
      acc1 = __builtin_amdgcn_mfma_f32_32x32x16_bf16(a, h1, acc1, 0, 0, 0);
    }
    __syncthreads();
  }
  // epilogue: (acc + b2) * wt -> bf16 -> LDS bounce (Xs area) [tok][c]
#pragma unroll
  for (int rq = 0; rq < 4; ++rq) {
    int c0 = w * 32 + 8 * rq + 4 * hi;
    float4 b2v = *(const float4*)(b2g + e * 512 + c0);
    {
      int tok = l31;
      float wt = wts[tok];
      u32x2 p;
      p.x = (unsigned)f2bf((acc0[4 * rq + 0] + b2v.x) * wt) |
            ((unsigned)f2bf((acc0[4 * rq + 1] + b2v.y) * wt) << 16);
      p.y = (unsigned)f2bf((acc0[4 * rq + 2] + b2v.z) * wt) |
            ((unsigned)f2bf((acc0[4 * rq + 3] + b2v.w) * wt) << 16);
      *(u32x2*)(smem + tok * 1024 + ((c0 * 2) ^ ((tok & 7) << 4))) = p;
    }
    {
      int tok = 32 + l31;
      float wt = wts[tok];
      u32x2 p;
      p.x = (unsigned)f2bf((acc1[4 * rq + 0] + b2v.x) * wt) |
            ((unsigned)f2bf((acc1[4 * rq + 1] + b2v.y) * wt) << 16);
      p.y = (unsigned)f2bf((acc1[4 * rq + 2] + b2v.z) * wt) |
            ((unsigned)f2bf((acc1[4 * rq + 3] + b2v.w) * wt) << 16);
      *(u32x2*)(smem + tok * 1024 + ((c0 * 2) ^ ((tok & 7) << 4))) = p;
    }
  }
  __syncthreads();
  // copy out rows [0, valid)
#pragma unroll
  for (int s = 0; s < 4; ++s) {
    int i = tid + s * 1024;
    int row = i >> 6, g = i & 63;
    if (row < valid) {
      u32x4 v = *(u32x4*)(smem + row * 1024 + ((g * 16) ^ ((row & 7) << 4)));
      *(u32x4*)(Yb + (size_t)(base + row) * 512 + g * 8) = v;
    }
  }
}

// ---------------------------------------------------------------------------
// K8: head bf16 MFMA GEMM. M=8192, N=256, K=512. A[tok] = Yb[p1]+Yb[p2].
// 128x128 tile (grid 64x2), 256 thr / 4 waves, wave tile 64x64.
// ---------------------------------------------------------------------------
__global__ __launch_bounds__(256) void k_head(const unsigned short* __restrict__ Yb,
                                              const int* __restrict__ tokpos,
                                              const unsigned short* __restrict__ headPk,
                                              const float* __restrict__ headB,
                                              float* __restrict__ out) {
  __shared__ __align__(16) char As[16384];  // [128 rows][64 k] bf16 swizzled
  __shared__ int tp[256];
  int tid = threadIdx.x;
  int w = tid >> 6, l = tid & 63;
  int l31 = l & 31, hi = l >> 5;
  int mg = w & 1, ng = w >> 1;
  int bm = blockIdx.x * 128, by = blockIdx.y;
  tp[tid] = tokpos[bm * 2 + tid];
  f32x16 acc00, acc01, acc10, acc11;
#pragma unroll
  for (int i = 0; i < 16; ++i) { acc00[i] = 0.f; acc01[i] = 0.f; acc10[i] = 0.f; acc11[i] = 0.f; }
  int nblk0 = by * 4 + ng * 2;
  __syncthreads();
  for (int kb = 0; kb < 8; ++kb) {
#pragma unroll
    for (int s = 0; s < 4; ++s) {
      int i = tid + s * 256;
      int row = i >> 3, g = i & 7;
      int p1 = tp[row * 2], p2 = tp[row * 2 + 1];
      u32x4 va = *(const u32x4*)(Yb + (size_t)p1 * 512 + kb * 64 + g * 8);
      u32x4 vb = *(const u32x4*)(Yb + (size_t)p2 * 512 + kb * 64 + g * 8);
      u32x4 o;
      o.x = (unsigned)f2bf(bflo(va.x) + bflo(vb.x)) | ((unsigned)f2bf(bfhi(va.x) + bfhi(vb.x)) << 16);
      o.y = (unsigned)f2bf(bflo(va.y) + bflo(vb.y)) | ((unsigned)f2bf(bfhi(va.y) + bfhi(vb.y)) << 16);
      o.z = (unsigned)f2bf(bflo(va.z) + bflo(vb.z)) | ((unsigned)f2bf(bfhi(va.z) + bfhi(vb.z)) << 16);
      o.w = (unsigned)f2bf(bflo(va.w) + bflo(vb.w)) | ((unsigned)f2bf(bfhi(va.w) + bfhi(vb.w)) << 16);
      *(u32x4*)(As + row * 128 + ((g * 16) ^ ((row & 7) << 4))) = o;
    }
    __syncthreads();
#pragma unroll
    for (int ks = 0; ks < 4; ++ks) {
      int r0 = mg * 64 + l31, r1 = r0 + 32;
      int kbyte = ks * 32 + hi * 16;
      bf16x8 a0 = ld_frag(As + r0 * 128 + (kbyte ^ ((r0 & 7) << 4)));
      bf16x8 a1 = ld_frag(As + r1 * 128 + (kbyte ^ ((r1 & 7) << 4)));
      const unsigned short* hp = headPk + ((size_t)nblk0 * 32 + kb * 4 + ks) * 512 + l * 8;
      bf16x8 b0 = *(const bf16x8*)hp;
      bf16x8 b1 = *(const bf16x8*)(hp + 32 * 512);
      acc00 = __builtin_amdgcn_mfma_f32_32x32x16_bf16(a0, b0, acc00, 0, 0, 0);
      acc01 = __builtin_amdgcn_mfma_f32_32x32x16_bf16(a0, b1, acc01, 0, 0, 0);
      acc10 = __builtin_amdgcn_mfma_f32_32x32x16_bf16(a1, b0, acc10, 0, 0, 0);
      acc11 = __builtin_amdgcn_mfma_f32_32x32x16_bf16(a1, b1, acc11, 0, 0, 0);
    }
    __syncthreads();
  }
  // epilogue: D col = n (lane), rows m; +bias; coalesced f32 stores
#pragma unroll
  for (int mf = 0; mf < 2; ++mf) {
#pragma unroll
    for (int nf = 0; nf < 2; ++nf) {
      int nc = by * 128 + ng * 64 + nf * 32 + l31;
      float hb = headB[nc];
#pragma unroll
      for (int r = 0; r < 16; ++r) {
        int m = bm + mg * 64 + mf * 32 + (r & 3) + 8 * (r >> 2) + 4 * hi;
        float v;
        if (mf == 0) v = (nf == 0) ? acc00[r] : acc01[r];
        else         v = (nf == 0) ? acc10[r] : acc11[r];
        out[(size_t)m * 256 + nc] = v + hb;
      }
    }
  }
}

extern "C" void kernel_launch(void* const* d_in, const int* in_sizes, int n_in,
                              void* d_out, int out_size, void* d_ws, size_t ws_size,
                              hipStream_t stream) {
  (void)in_sizes; (void)n_in; (void)out_size; (void)ws_size;
  const int* seq     = (const int*)d_in[0];
  const float* emb   = (const float*)d_in[1];
  const float* phi_w = (const float*)d_in[2];
  const float* phi_b = (const float*)d_in[3];
  const float* amp_w = (const float*)d_in[4];
  const float* amp_b = (const float*)d_in[5];
  const float* gate_w = (const float*)d_in[6];
  const float* gate_b = (const float*)d_in[7];
  const float* w1 = (const float*)d_in[8];
  const float* b1 = (const float*)d_in[9];
  const float* w2 = (const float*)d_in[10];
  const float* b2 = (const float*)d_in[11];
  const float* head_w = (const float*)d_in[12];
  const float* head_b = (const float*)d_in[13];
  float* out = (float*)d_out;

  char* ws = (char*)d_ws;
  const size_t BUF = 16777216;
  float* X    = (float*)(ws);                         // X -> xmoe (in place)
  float* COSb = (float*)(ws + BUF);                   // cos -> Yb (bf16)
  float* SINb = (float*)(ws + 2 * BUF);               // sin -> W1Pk (bf16)
  float* SIGb = (float*)(ws + 3 * BUF);               // sig -> W2Pk (bf16)
  unsigned short* Yb   = (unsigned short*)COSb;
  unsigned short* W1Pk = (unsigned short*)SINb;
  unsigned short* W2Pk = (unsigned short*)SIGb;
  char* sm = ws + 4 * BUF;
  int*      e01p   = (int*)(sm);                      // 32KB
  unsigned* w01p   = (unsigned*)(sm + 32768);         // 32KB
  int*      list   = (int*)(sm + 65536);              // 64KB
  float*    wlist  = (float*)(sm + 131072);           // 64KB
  int*      tokpos = (int*)(sm + 196608);             // 64KB
  int*      counts = (int*)(sm + 262144);
  int*      eoff   = (int*)(sm + 262144 + 64);
  unsigned short* headPk = (unsigned short*)(sm + 266240);  // 256KB

  k_embed<<<4096, 256, 0, stream>>>(seq, emb, X);
  // pack head_w [512][256] -> 8 nblk frags
  k_pack_b<<<dim3(8, 1, 1), 256, 0, stream>>>(head_w, 256, 0, headPk, 0, 32);
  // fused phi+amp fp32 GEMM (64x128 tiles, 1024 blocks)
  k_phi<<<dim3(128, 8), 256, 0, stream>>>(X, phi_w, phi_b, amp_w, amp_b, COSb, SINb, SIGb);
  k_scan<<<32, 64, 0, stream>>>(COSb, SINb, SIGb, X, out + 2097152);
  // pack w1 [e][512][2048], w2 [e][2048][512] (after scan frees SINb/SIGb)
  k_pack_b<<<dim3(64, 1, 8), 256, 0, stream>>>(w1, 2048, (size_t)512 * 2048, W1Pk,
                                               (size_t)64 * 32 * 512, 32);
  k_pack_b<<<dim3(16, 4, 8), 256, 0, stream>>>(w2, 512, (size_t)2048 * 512, W2Pk,
                                               (size_t)16 * 128 * 512, 128);
  k_gate<<<256, 256, 0, stream>>>(X, gate_w, gate_b, e01p, w01p);
  k_build<<<1, 256, 0, stream>>>(e01p, w01p, list, wlist, counts, eoff, tokpos);
  // full coverage: counts[e] <= 8192 always (top-2 experts distinct per token)
  k_ffn<<<dim3(128, 8), 1024, 0, stream>>>(X, list, wlist, counts, eoff,
                                           W1Pk, b1, W2Pk, b2, Yb);
  k_head<<<dim3(64, 2), 256, 0, stream>>>(Yb, tokpos, headPk, head_b, out);
}

// Round 6
// 682.737 us; speedup vs baseline: 1.0887x; 1.0887x over previous
//
#include <hip/hip_runtime.h>
#include <hip/hip_fp16.h>
#include <math.h>

// ---------------------------------------------------------------------------
// SovereignLeviathanV2  round 6 = round 5 with k_phi rewritten:
//  128x128 tile, 8x8 micro (16 FMA per ds_read_b128), k-major swizzled LDS
//  (conflict-free, 16B-aligned), 16-load + 256-FMA bursts for single-wave ILP.
// Everything else byte-identical to the passing round-5 kernel.
// ---------------------------------------------------------------------------

#define PI_F 3.14159265358979323846f
#define HARM_F 1.04719755119659774615f
#define INV_HARM_F 0.95492965855137201461f
#define TOL_F 0.15f

typedef float f32x16 __attribute__((ext_vector_type(16)));
typedef __bf16 bf16x8 __attribute__((ext_vector_type(8)));
typedef unsigned int u32x4 __attribute__((ext_vector_type(4)));
typedef unsigned int u32x2 __attribute__((ext_vector_type(2)));

__device__ __forceinline__ float gelu_tanh(float x) {
  float x3 = x * x * x;
  return 0.5f * x * (1.f + tanhf(0.79788456080286535588f * (x + 0.044715f * x3)));
}
__device__ __forceinline__ unsigned short f2bf(float x) {
  unsigned u = __float_as_uint(x);
  unsigned r = (u + 0x7FFFu + ((u >> 16) & 1u)) >> 16;
  return (unsigned short)r;
}
__device__ __forceinline__ float bflo(unsigned u) { return __uint_as_float(u << 16); }
__device__ __forceinline__ float bfhi(unsigned u) { return __uint_as_float(u & 0xFFFF0000u); }
__device__ __forceinline__ bf16x8 ld_frag(const void* p) {
  u32x4 v = *(const u32x4*)p;
  return __builtin_bit_cast(bf16x8, v);
}

// K1: X[n][c] = emb[seq[n]][c]
__global__ void k_embed(const int* __restrict__ seq, const float* __restrict__ emb,
                        float* __restrict__ X) {
  int i = blockIdx.x * 256 + threadIdx.x;
  int n = i >> 7, c4 = i & 127;
  int tok = seq[n];
  ((float4*)X)[(size_t)n * 128 + c4] = ((const float4*)emb)[(size_t)tok * 128 + c4];
}

// ---------------------------------------------------------------------------
// Generic B-operand frag pack (unchanged)
// ---------------------------------------------------------------------------
__global__ __launch_bounds__(256) void k_pack_b(const float* __restrict__ src, int ld,
                                                size_t srcE, unsigned short* __restrict__ dst,
                                                size_t dstE, int fragKtot) {
  __shared__ float Ls[512 * 33];
  int nb = blockIdx.x, kseg = blockIdx.y, e = blockIdx.z;
  const float* s = src + (size_t)e * srcE + (size_t)kseg * 512 * ld + nb * 32;
  unsigned short* d = dst + (size_t)e * dstE + ((size_t)(nb * fragKtot + kseg * 32)) * 512;
  int tid = threadIdx.x;
#pragma unroll
  for (int q = 0; q < 16; ++q) {
    int i = tid + q * 256;
    int row = i >> 3, c4 = i & 7;
    float4 v = *(const float4*)(s + (size_t)row * ld + c4 * 4);
    Ls[row * 33 + c4 * 4 + 0] = v.x;
    Ls[row * 33 + c4 * 4 + 1] = v.y;
    Ls[row * 33 + c4 * 4 + 2] = v.z;
    Ls[row * 33 + c4 * 4 + 3] = v.w;
  }
  __syncthreads();
#pragma unroll
  for (int q = 0; q < 8; ++q) {
    int i = tid + q * 256;
    int ks = i >> 6, l = i & 63;
    int col = l & 31, kb = (l >> 5) * 8 + ks * 16;
    u32x4 o;
    o.x = (unsigned)f2bf(Ls[(kb + 0) * 33 + col]) | ((unsigned)f2bf(Ls[(kb + 1) * 33 + col]) << 16);
    o.y = (unsigned)f2bf(Ls[(kb + 2) * 33 + col]) | ((unsigned)f2bf(Ls[(kb + 3) * 33 + col]) << 16);
    o.z = (unsigned)f2bf(Ls[(kb + 4) * 33 + col]) | ((unsigned)f2bf(Ls[(kb + 5) * 33 + col]) << 16);
    o.w = (unsigned)f2bf(Ls[(kb + 6) * 33 + col]) | ((unsigned)f2bf(Ls[(kb + 7) * 33 + col]) << 16);
    *(u32x4*)(d + (size_t)ks * 512 + l * 8) = o;
  }
}

// ---------------------------------------------------------------------------
// K2: fused phi+amp fp32 GEMM. M=8192, K=512, N=1024 (by<4: phi, else amp).
// 128x128 tile, BK=16, 8x8 micro. LDS k-major + XOR k-quad swizzle:
//   As elem (m,k) at  m*16 + ((k>>2) ^ ((m>>3)&3))*4 + (k&3)
//   Bs elem (n,k) at  n*16 + ((k>>2) ^ ((n>>1)&3))*4 + (k&3)
// Micro rows = ty*8+j (4 addrs/wave, distinct quads -> conflict-free);
// micro cols = j*16+tx (16 addrs/wave, <=2-way -> free).
// Per kq: 16 x ds_read_b128 then 256 FMA (single-wave ILP burst).
// ---------------------------------------------------------------------------
__global__ __launch_bounds__(256, 2) void k_phi(const float* __restrict__ A,
                                                const float* __restrict__ phiW,
                                                const float* __restrict__ phiB,
                                                const float* __restrict__ ampW,
                                                const float* __restrict__ ampB,
                                                float* __restrict__ cosO,
                                                float* __restrict__ sinO,
                                                float* __restrict__ sigO) {
  __shared__ float As[2][128 * 16];
  __shared__ float Bs[2][128 * 16];
  int tid = threadIdx.x;
  int tx = tid & 15, ty = tid >> 4;
  int bm = blockIdx.x * 128;
  int by = blockIdx.y;
  const float* Bsrc = (by < 4) ? phiW : ampW;
  const float* bias = (by < 4) ? phiB : ampB;
  int cb = (by & 3) * 128;
  float acc[8][8];
#pragma unroll
  for (int r = 0; r < 8; ++r)
#pragma unroll
    for (int c = 0; c < 8; ++c) acc[r][c] = 0.f;

#define STAGE_PHI(BUF, KT)                                                     \
  {                                                                            \
    _Pragma("unroll") for (int s = 0; s < 2; ++s) {                            \
      int i = tid + s * 256;                                                   \
      int row = i >> 2, kq = i & 3;                                            \
      float4 v = *(const float4*)(A + (size_t)(bm + row) * 512 + (KT)*16 + kq * 4); \
      *(float4*)(&As[BUF][row * 16 + ((kq ^ ((row >> 3) & 3)) << 2)]) = v;     \
    }                                                                          \
    _Pragma("unroll") for (int s = 0; s < 2; ++s) {                            \
      int i = tid + s * 256;                                                   \
      int kk = i >> 5, g = i & 31;                                             \
      float4 v = *(const float4*)(Bsrc + (size_t)((KT)*16 + kk) * 512 + cb + g * 4); \
      int kq = kk >> 2, kr = kk & 3;                                           \
      float vv[4] = {v.x, v.y, v.z, v.w};                                      \
      _Pragma("unroll") for (int q = 0; q < 4; ++q) {                          \
        int n = g * 4 + q;                                                     \
        Bs[BUF][n * 16 + ((kq ^ ((n >> 1) & 3)) << 2) + kr] = vv[q];           \
      }                                                                        \
    }                                                                          \
  }

  STAGE_PHI(0, 0);
  for (int kt = 0; kt < 32; ++kt) {
    __syncthreads();
    if (kt + 1 < 32) {
      if ((kt & 1) == 0) STAGE_PHI(1, kt + 1) else STAGE_PHI(0, kt + 1)
    }
    const float* Ab = As[kt & 1];
    const float* Bb = Bs[kt & 1];
#pragma unroll
    for (int kq = 0; kq < 4; ++kq) {
      float4 af[8], bf[8];
#pragma unroll
      for (int j = 0; j < 8; ++j) {
        int m = ty * 8 + j;
        af[j] = *(const float4*)(&Ab[m * 16 + ((kq ^ ((m >> 3) & 3)) << 2)]);
        int n = j * 16 + tx;
        bf[j] = *(const float4*)(&Bb[n * 16 + ((kq ^ ((n >> 1) & 3)) << 2)]);
      }
      const float* afp = (const float*)af;
      const float* bfp = (const float*)bf;
#pragma unroll
      for (int kk = 0; kk < 4; ++kk)
#pragma unroll
        for (int r = 0; r < 8; ++r)
#pragma unroll
          for (int c = 0; c < 8; ++c)
            acc[r][c] = fmaf(afp[r * 4 + kk], bfp[c * 4 + kk], acc[r][c]);
    }
  }
  // epilogue: rows m = bm+ty*8+r; cols col = cb + c*16 + tx
#pragma unroll
  for (int r = 0; r < 8; ++r) {
    int m = bm + ty * 8 + r;
    if (by < 4) {
      float* cp = cosO + (size_t)m * 512 + cb + tx;
      float* sp = sinO + (size_t)m * 512 + cb + tx;
#pragma unroll
      for (int c = 0; c < 8; ++c) {
        float z = acc[r][c] + bias[cb + c * 16 + tx];
        float a = tanhf(z) * PI_F;
        float nr = rintf(a * INV_HARM_F) * HARM_F;
        if (fabsf(a - nr) < TOL_F) a = nr;
        float sn, cs;
        sincosf(a, &sn, &cs);
        cp[c * 16] = cs;
        sp[c * 16] = sn;
      }
    } else {
      float* gp = sigO + (size_t)m * 512 + cb + tx;
#pragma unroll
      for (int c = 0; c < 8; ++c) {
        float z = acc[r][c] + bias[cb + c * 16 + tx];
        gp[c * 16] = 1.f / (1.f + expf(-z));
      }
    }
  }
}

// K3: toroidal scan, 4-buffer rotating prefetch. 32 blocks x 64 threads.
__global__ void k_scan(const float* __restrict__ cosb, const float* __restrict__ sinb,
                       const float* __restrict__ sigb, float* __restrict__ xmoe,
                       float* __restrict__ nstate) {
  int gid = blockIdx.x * 64 + threadIdx.x;  // 0..2047
  size_t b = gid >> 9, c = gid & 511;
  size_t base = (b * 2048) * 512 + c;
  float state = 0.f;
  float C0[8], S0[8], G0[8], C1[8], S1[8], G1[8];
  float C2[8], S2[8], G2[8], C3[8], S3[8], G3[8];
#define LOADB(CB, SB, GB, blk)                                                  \
  {                                                                             \
    int bb = (blk) < 255 ? (blk) : 255;                                         \
    size_t o = base + (size_t)bb * 8 * 512;                                     \
    _Pragma("unroll") for (int j = 0; j < 8; ++j) {                             \
      size_t oo = o + (size_t)j * 512;                                          \
      CB[j] = cosb[oo]; SB[j] = sinb[oo]; GB[j] = sigb[oo];                     \
    }                                                                           \
  }
#define COMPB(CB, SB, GB, blk)                                                  \
  {                                                                             \
    size_t o = base + (size_t)(blk)*8 * 512;                                    \
    _Pragma("unroll") for (int j = 0; j < 8; ++j) {                             \
      float st = fmaf(SB[j], state, -SB[j]);                                    \
      st = fmaf(CB[j], state, st);                                              \
      st = fminf(1.f, fmaxf(-1.f, st));                                         \
      state = st;                                                               \
      xmoe[o + (size_t)j * 512] = GB[j] * st;                                   \
    }                                                                           \
  }
  LOADB(C0, S0, G0, 0);
  LOADB(C1, S1, G1, 1);
  LOADB(C2, S2, G2, 2);
  for (int i = 0; i < 64; ++i) {
    LOADB(C3, S3, G3, 4 * i + 3);
    COMPB(C0, S0, G0, 4 * i);
    LOADB(C0, S0, G0, 4 * i + 4);
    COMPB(C1, S1, G1, 4 * i + 1);
    LOADB(C1, S1, G1, 4 * i + 5);
    COMPB(C2, S2, G2, 4 * i + 2);
    LOADB(C2, S2, G2, 4 * i + 6);
    COMPB(C3, S3, G3, 4 * i + 3);
  }
  nstate[gid] = state;
}

// K4: gate logits + softmax + top2 -> packed e01p/w01p
__global__ __launch_bounds__(256) void k_gate(const float* __restrict__ xmoe,
                                              const float* __restrict__ gw_g,
                                              const float* __restrict__ gb,
                                              int* __restrict__ e01p,
                                              unsigned* __restrict__ w01p) {
  __shared__ float gw[4096];
  int tid = threadIdx.x;
  for (int i = tid; i < 4096; i += 256) gw[i] = gw_g[i];
  __syncthreads();
  int tok = blockIdx.x * 32 + (tid >> 3);
  int e = tid & 7;
  float acc = gb[e];
  const float4* xr = (const float4*)(xmoe + (size_t)tok * 512);
  for (int k4 = 0; k4 < 128; ++k4) {
    float4 x = xr[k4];
    acc += x.x * gw[(k4 * 4 + 0) * 8 + e];
    acc += x.y * gw[(k4 * 4 + 1) * 8 + e];
    acc += x.z * gw[(k4 * 4 + 2) * 8 + e];
    acc += x.w * gw[(k4 * 4 + 3) * 8 + e];
  }
  float m = acc;
  m = fmaxf(m, __shfl_xor(m, 1));
  m = fmaxf(m, __shfl_xor(m, 2));
  m = fmaxf(m, __shfl_xor(m, 4));
  float p = expf(acc - m);
  float ss = p;
  ss += __shfl_xor(ss, 1); ss += __shfl_xor(ss, 2); ss += __shfl_xor(ss, 4);
  p /= ss;
  float v1 = p; int i1 = e;
  {
    float ov; int oi;
    ov = __shfl_xor(v1, 1); oi = __shfl_xor(i1, 1);
    if (ov > v1 || (ov == v1 && oi < i1)) { v1 = ov; i1 = oi; }
    ov = __shfl_xor(v1, 2); oi = __shfl_xor(i1, 2);
    if (ov > v1 || (ov == v1 && oi < i1)) { v1 = ov; i1 = oi; }
    ov = __shfl_xor(v1, 4); oi = __shfl_xor(i1, 4);
    if (ov > v1 || (ov == v1 && oi < i1)) { v1 = ov; i1 = oi; }
  }
  float v2 = (e == i1) ? -1.f : p; int i2 = e;
  {
    float ov; int oi;
    ov = __shfl_xor(v2, 1); oi = __shfl_xor(i2, 1);
    if (ov > v2 || (ov == v2 && oi < i2)) { v2 = ov; i2 = oi; }
    ov = __shfl_xor(v2, 2); oi = __shfl_xor(i2, 2);
    if (ov > v2 || (ov == v2 && oi < i2)) { v2 = ov; i2 = oi; }
    ov = __shfl_xor(v2, 4); oi = __shfl_xor(i2, 4);
    if (ov > v2 || (ov == v2 && oi < i2)) { v2 = ov; i2 = oi; }
  }
  if (e == 0) {
    float s2 = v1 + v2;
    __half h1 = __float2half(v1 / s2), h2 = __float2half(v2 / s2);
    e01p[tok] = i1 | (i2 << 8);
    w01p[tok] = (unsigned)__half_as_ushort(h1) | ((unsigned)__half_as_ushort(h2) << 16);
  }
}

// K6: counts -> eoff prefix -> scatter (list/wlist/tokpos), 1 block
__global__ void k_build(const int* __restrict__ e01p, const unsigned* __restrict__ w01p,
                        int* __restrict__ list, float* __restrict__ wlist,
                        int* __restrict__ counts, int* __restrict__ eoff,
                        int* __restrict__ tokpos) {
  __shared__ int cnt[8], cur[8];
  int tid = threadIdx.x, lane = tid & 63;
  if (tid < 8) cnt[tid] = 0;
  __syncthreads();
  for (int i = tid; i < 16384; i += 256) {
    int tok = i >> 1, j = i & 1;
    int ee = (e01p[tok] >> (8 * j)) & 255;
#pragma unroll
    for (int x = 0; x < 8; ++x) {
      unsigned long long m = __ballot(ee == x);
      if (m != 0ull && lane == (__ffsll((long long)m) - 1)) atomicAdd(&cnt[x], __popcll(m));
    }
  }
  __syncthreads();
  if (tid == 0) {
    int s = 0;
#pragma unroll
    for (int x = 0; x < 8; ++x) {
      cur[x] = s; eoff[x] = s; counts[x] = cnt[x]; s += cnt[x];
    }
  }
  __syncthreads();
  for (int i = tid; i < 16384; i += 256) {
    int tok = i >> 1, j = i & 1;
    int ee = (e01p[tok] >> (8 * j)) & 255;
    unsigned wp = w01p[tok];
    unsigned short us = (unsigned short)(j ? (wp >> 16) : (wp & 0xFFFFu));
    float w = __half2float(__ushort_as_half(us));
    int pos = 0;
#pragma unroll
    for (int x = 0; x < 8; ++x) {
      unsigned long long m = __ballot(ee == x);
      if (m == 0ull) continue;
      int leader = __ffsll((long long)m) - 1;
      int bb = 0;
      if (lane == leader) bb = atomicAdd(&cur[x], __popcll(m));
      bb = __shfl(bb, leader);
      if (ee == x) pos = bb + __popcll(m & ((1ull << lane) - 1ull));
    }
    list[pos] = tok;
    wlist[pos] = w;
    tokpos[i] = pos;
  }
}

// ---------------------------------------------------------------------------
// K7: fused MoE FFN (unchanged from round 5). 1024 thr / 16 waves.
// ---------------------------------------------------------------------------
#define HS_OFF 65536

__global__ __launch_bounds__(1024, 4) void k_ffn(
    const float* __restrict__ xmoe, const int* __restrict__ list,
    const float* __restrict__ wlist, const int* __restrict__ counts,
    const int* __restrict__ eoff,
    const unsigned short* __restrict__ W1Pk, const float* __restrict__ b1g,
    const unsigned short* __restrict__ W2Pk, const float* __restrict__ b2g,
    unsigned short* __restrict__ Yb) {
  int e = blockIdx.y, tile = blockIdx.x;
  int cnt = counts[e];
  if (tile * 64 >= cnt) return;
  int base = eoff[e] + tile * 64;
  int valid = cnt - tile * 64;
  if (valid > 64) valid = 64;
  __shared__ __align__(16) char smem[131072];
  __shared__ int toks[64];
  __shared__ float wts[64];
  int tid = threadIdx.x;
  int w = tid >> 6, l = tid & 63;
  int l31 = l & 31, hi = l >> 5;
  int sw = (l31 & 7) << 4;
  if (tid < 64) {
    int idx = tile * 64 + tid;
    bool v = idx < cnt;
    toks[tid] = list[eoff[e] + (v ? idx : 0)];
    wts[tid] = v ? wlist[eoff[e] + idx] : 0.f;
  }
  __syncthreads();
#pragma unroll
  for (int s = 0; s < 4; ++s) {
    int i = tid + s * 1024;
    int row = i >> 6, g = i & 63;
    const float* src = xmoe + (size_t)toks[row] * 512 + g * 8;
    float4 v0 = *(const float4*)src;
    float4 v1 = *(const float4*)(src + 4);
    u32x4 u;
    u.x = (unsigned)f2bf(v0.x) | ((unsigned)f2bf(v0.y) << 16);
    u.y = (unsigned)f2bf(v0.z) | ((unsigned)f2bf(v0.w) << 16);
    u.z = (unsigned)f2bf(v1.x) | ((unsigned)f2bf(v1.y) << 16);
    u.w = (unsigned)f2bf(v1.z) | ((unsigned)f2bf(v1.w) << 16);
    *(u32x4*)(smem + row * 1024 + ((g * 16) ^ ((row & 7) << 4))) = u;
  }
  f32x16 acc0, acc1;
#pragma unroll
  for (int i = 0; i < 16; ++i) { acc0[i] = 0.f; acc1[i] = 0.f; }
  __syncthreads();

  for (int it = 0; it < 4; ++it) {
    f32x16 z0, z1;
#pragma unroll
    for (int i = 0; i < 16; ++i) { z0[i] = 0.f; z1[i] = 0.f; }
    const unsigned short* w1p =
        W1Pk + (((size_t)e * 64 + it * 16 + w) * 32) * 512 + l * 8;
#pragma unroll 8
    for (int ks = 0; ks < 32; ++ks) {
      bf16x8 a = *(const bf16x8*)(w1p + (size_t)ks * 512);
      int kb = ks * 32 + hi * 16;
      bf16x8 b0 = ld_frag(smem + l31 * 1024 + (kb ^ sw));
      bf16x8 b1 = ld_frag(smem + (l31 + 32) * 1024 + (kb ^ sw));
      z0 = __builtin_amdgcn_mfma_f32_32x32x16_bf16(a, b0, z0, 0, 0, 0);
      z1 = __builtin_amdgcn_mfma_f32_32x32x16_bf16(a, b1, z1, 0, 0, 0);
    }
#pragma unroll
    for (int rq = 0; rq < 4; ++rq) {
      int f0 = 8 * rq + 4 * hi;
      float4 bv = *(const float4*)(b1g + e * 2048 + it * 512 + w * 32 + f0);
      float g0 = gelu_tanh(z0[4 * rq + 0] + bv.x);
      float g1 = gelu_tanh(z0[4 * rq + 1] + bv.y);
      float g2 = gelu_tanh(z0[4 * rq + 2] + bv.z);
      float g3 = gelu_tanh(z0[4 * rq + 3] + bv.w);
      u32x2 p;
      p.x = (unsigned)f2bf(g0) | ((unsigned)f2bf(g1) << 16);
      p.y = (unsigned)f2bf(g2) | ((unsigned)f2bf(g3) << 16);
      *(u32x2*)(smem + HS_OFF + l31 * 1024 + (((w * 32 + f0) * 2) ^ sw)) = p;
      g0 = gelu_tanh(z1[4 * rq + 0] + bv.x);
      g1 = gelu_tanh(z1[4 * rq + 1] + bv.y);
      g2 = gelu_tanh(z1[4 * rq + 2] + bv.z);
      g3 = gelu_tanh(z1[4 * rq + 3] + bv.w);
      p.x = (unsigned)f2bf(g0) | ((unsigned)f2bf(g1) << 16);
      p.y = (unsigned)f2bf(g2) | ((unsigned)f2bf(g3) << 16);
      *(u32x2*)(smem + HS_OFF + (l31 + 32) * 1024 + (((w * 32 + f0) * 2) ^ sw)) = p;
    }
    __syncthreads();
    const unsigned short* w2p =
        W2Pk + (((size_t)e * 16 + w) * 128 + it * 32) * 512 + l * 8;
#pragma unroll 8
    for (int fs = 0; fs < 32; ++fs) {
      bf16x8 a = *(const bf16x8*)(w2p + (size_t)fs * 512);
      int fb = fs * 32 + hi * 16;
      bf16x8 h0 = ld_frag(smem + HS_OFF + l31 * 1024 + (fb ^ sw));
      bf16x8 h1 = ld_frag(smem + HS_OFF + (l31 + 32) * 1024 + (fb ^ sw));
      acc0 = __builtin_amdgcn_mfma_f32_32x32x16_bf16(a, h0, acc0, 0, 0, 0);
      acc1 = __builtin_amdgcn_mfma_f32_32x32x16_bf16(a, h1, acc1, 0, 0, 0);
    }
    __syncthreads();
  }
#pragma unroll
  for (int rq = 0; rq < 4; ++rq) {
    int c0 = w * 32 + 8 * rq + 4 * hi;
    float4 b2v = *(const float4*)(b2g + e * 512 + c0);
    {
      int tok = l31;
      float wt = wts[tok];
      u32x2 p;
      p.x = (unsigned)f2bf((acc0[4 * rq + 0] + b2v.x) * wt) |
            ((unsigned)f2bf((acc0[4 * rq + 1] + b2v.y) * wt) << 16);
      p.y = (unsigned)f2bf((acc0[4 * rq + 2] + b2v.z) * wt) |
            ((unsigned)f2bf((acc0[4 * rq + 3] + b2v.w) * wt) << 16);
      *(u32x2*)(smem + tok * 1024 + ((c0 * 2) ^ ((tok & 7) << 4))) = p;
    }
    {
      int tok = 32 + l31;
      float wt = wts[tok];
      u32x2 p;
      p.x = (unsigned)f2bf((acc1[4 * rq + 0] + b2v.x) * wt) |
            ((unsigned)f2bf((acc1[4 * rq + 1] + b2v.y) * wt) << 16);
      p.y = (unsigned)f2bf((acc1[4 * rq + 2] + b2v.z) * wt) |
            ((unsigned)f2bf((acc1[4 * rq + 3] + b2v.w) * wt) << 16);
      *(u32x2*)(smem + tok * 1024 + ((c0 * 2) ^ ((tok & 7) << 4))) = p;
    }
  }
  __syncthreads();
#pragma unroll
  for (int s = 0; s < 4; ++s) {
    int i = tid + s * 1024;
    int row = i >> 6, g = i & 63;
    if (row < valid) {
      u32x4 v = *(u32x4*)(smem + row * 1024 + ((g * 16) ^ ((row & 7) << 4)));
      *(u32x4*)(Yb + (size_t)(base + row) * 512 + g * 8) = v;
    }
  }
}

// ---------------------------------------------------------------------------
// K8: head bf16 MFMA GEMM (unchanged)
// ---------------------------------------------------------------------------
__global__ __launch_bounds__(256) void k_head(const unsigned short* __restrict__ Yb,
                                              const int* __restrict__ tokpos,
                                              const unsigned short* __restrict__ headPk,
                                              const float* __restrict__ headB,
                                              float* __restrict__ out) {
  __shared__ __align__(16) char As[16384];
  __shared__ int tp[256];
  int tid = threadIdx.x;
  int w = tid >> 6, l = tid & 63;
  int l31 = l & 31, hi = l >> 5;
  int mg = w & 1, ng = w >> 1;
  int bm = blockIdx.x * 128, by = blockIdx.y;
  tp[tid] = tokpos[bm * 2 + tid];
  f32x16 acc00, acc01, acc10, acc11;
#pragma unroll
  for (int i = 0; i < 16; ++i) { acc00[i] = 0.f; acc01[i] = 0.f; acc10[i] = 0.f; acc11[i] = 0.f; }
  int nblk0 = by * 4 + ng * 2;
  __syncthreads();
  for (int kb = 0; kb < 8; ++kb) {
#pragma unroll
    for (int s = 0; s < 4; ++s) {
      int i = tid + s * 256;
      int row = i >> 3, g = i & 7;
      int p1 = tp[row * 2], p2 = tp[row * 2 + 1];
      u32x4 va = *(const u32x4*)(Yb + (size_t)p1 * 512 + kb * 64 + g * 8);
      u32x4 vb = *(const u32x4*)(Yb + (size_t)p2 * 512 + kb * 64 + g * 8);
      u32x4 o;
      o.x = (unsigned)f2bf(bflo(va.x) + bflo(vb.x)) | ((unsigned)f2bf(bfhi(va.x) + bfhi(vb.x)) << 16);
      o.y = (unsigned)f2bf(bflo(va.y) + bflo(vb.y)) | ((unsigned)f2bf(bfhi(va.y) + bfhi(vb.y)) << 16);
      o.z = (unsigned)f2bf(bflo(va.z) + bflo(vb.z)) | ((unsigned)f2bf(bfhi(va.z) + bfhi(vb.z)) << 16);
      o.w = (unsigned)f2bf(bflo(va.w) + bflo(vb.w)) | ((unsigned)f2bf(bfhi(va.w) + bfhi(vb.w)) << 16);
      *(u32x4*)(As + row * 128 + ((g * 16) ^ ((row & 7) << 4))) = o;
    }
    __syncthreads();
#pragma unroll
    for (int ks = 0; ks < 4; ++ks) {
      int r0 = mg * 64 + l31, r1 = r0 + 32;
      int kbyte = ks * 32 + hi * 16;
      bf16x8 a0 = ld_frag(As + r0 * 128 + (kbyte ^ ((r0 & 7) << 4)));
      bf16x8 a1 = ld_frag(As + r1 * 128 + (kbyte ^ ((r1 & 7) << 4)));
      const unsigned short* hp = headPk + ((size_t)nblk0 * 32 + kb * 4 + ks) * 512 + l * 8;
      bf16x8 b0 = *(const bf16x8*)hp;
      bf16x8 b1 = *(const bf16x8*)(hp + 32 * 512);
      acc00 = __builtin_amdgcn_mfma_f32_32x32x16_bf16(a0, b0, acc00, 0, 0, 0);
      acc01 = __builtin_amdgcn_mfma_f32_32x32x16_bf16(a0, b1, acc01, 0, 0, 0);
      acc10 = __builtin_amdgcn_mfma_f32_32x32x16_bf16(a1, b0, acc10, 0, 0, 0);
      acc11 = __builtin_amdgcn_mfma_f32_32x32x16_bf16(a1, b1, acc11, 0, 0, 0);
    }
    __syncthreads();
  }
#pragma unroll
  for (int mf = 0; mf < 2; ++mf) {
#pragma unroll
    for (int nf = 0; nf < 2; ++nf) {
      int nc = by * 128 + ng * 64 + nf * 32 + l31;
      float hb = headB[nc];
#pragma unroll
      for (int r = 0; r < 16; ++r) {
        int m = bm + mg * 64 + mf * 32 + (r & 3) + 8 * (r >> 2) + 4 * hi;
        float v;
        if (mf == 0) v = (nf == 0) ? acc00[r] : acc01[r];
        else         v = (nf == 0) ? acc10[r] : acc11[r];
        out[(size_t)m * 256 + nc] = v + hb;
      }
    }
  }
}

extern "C" void kernel_launch(void* const* d_in, const int* in_sizes, int n_in,
                              void* d_out, int out_size, void* d_ws, size_t ws_size,
                              hipStream_t stream) {
  (void)in_sizes; (void)n_in; (void)out_size; (void)ws_size;
  const int* seq     = (const int*)d_in[0];
  const float* emb   = (const float*)d_in[1];
  const float* phi_w = (const float*)d_in[2];
  const float* phi_b = (const float*)d_in[3];
  const float* amp_w = (const float*)d_in[4];
  const float* amp_b = (const float*)d_in[5];
  const float* gate_w = (const float*)d_in[6];
  const float* gate_b = (const float*)d_in[7];
  const float* w1 = (const float*)d_in[8];
  const float* b1 = (const float*)d_in[9];
  const float* w2 = (const float*)d_in[10];
  const float* b2 = (const float*)d_in[11];
  const float* head_w = (const float*)d_in[12];
  const float* head_b = (const float*)d_in[13];
  float* out = (float*)d_out;

  char* ws = (char*)d_ws;
  const size_t BUF = 16777216;
  float* X    = (float*)(ws);                         // X -> xmoe (in place)
  float* COSb = (float*)(ws + BUF);                   // cos -> Yb (bf16)
  float* SINb = (float*)(ws + 2 * BUF);               // sin -> W1Pk (bf16)
  float* SIGb = (float*)(ws + 3 * BUF);               // sig -> W2Pk (bf16)
  unsigned short* Yb   = (unsigned short*)COSb;
  unsigned short* W1Pk = (unsigned short*)SINb;
  unsigned short* W2Pk = (unsigned short*)SIGb;
  char* sm = ws + 4 * BUF;
  int*      e01p   = (int*)(sm);                      // 32KB
  unsigned* w01p   = (unsigned*)(sm + 32768);         // 32KB
  int*      list   = (int*)(sm + 65536);              // 64KB
  float*    wlist  = (float*)(sm + 131072);           // 64KB
  int*      tokpos = (int*)(sm + 196608);             // 64KB
  int*      counts = (int*)(sm + 262144);
  int*      eoff   = (int*)(sm + 262144 + 64);
  unsigned short* headPk = (unsigned short*)(sm + 266240);  // 256KB

  k_embed<<<4096, 256, 0, stream>>>(seq, emb, X);
  k_pack_b<<<dim3(8, 1, 1), 256, 0, stream>>>(head_w, 256, 0, headPk, 0, 32);
  k_phi<<<dim3(64, 8), 256, 0, stream>>>(X, phi_w, phi_b, amp_w, amp_b, COSb, SINb, SIGb);
  k_scan<<<32, 64, 0, stream>>>(COSb, SINb, SIGb, X, out + 2097152);
  k_pack_b<<<dim3(64, 1, 8), 256, 0, stream>>>(w1, 2048, (size_t)512 * 2048, W1Pk,
                                               (size_t)64 * 32 * 512, 32);
  k_pack_b<<<dim3(16, 4, 8), 256, 0, stream>>>(w2, 512, (size_t)2048 * 512, W2Pk,
                                               (size_t)16 * 128 * 512, 128);
  k_gate<<<256, 256, 0, stream>>>(X, gate_w, gate_b, e01p, w01p);
  k_build<<<1, 256, 0, stream>>>(e01p, w01p, list, wlist, counts, eoff, tokpos);
  k_ffn<<<dim3(128, 8), 1024, 0, stream>>>(X, list, wlist, counts, eoff,
                                           W1Pk, b1, W2Pk, b2, Yb);
  k_head<<<dim3(64, 2), 256, 0, stream>>>(Yb, tokpos, headPk, head_b, out);
}